// Round 13
// baseline (221.011 us; speedup 1.0000x reference)
//
#include <hip/hip_runtime.h>

#define NSEG 15872
#define DD 129
#define HH 128
#define NTILE (NSEG / 16)  // 992 node tiles

typedef __attribute__((ext_vector_type(8))) short s16x8;
typedef __attribute__((ext_vector_type(4))) short s16x4;
typedef __attribute__((ext_vector_type(4))) float f32x4;
typedef __attribute__((ext_vector_type(16))) float f32x16;

__device__ __forceinline__ unsigned short f2bf(float x) {
  union { float f; unsigned u; } c; c.f = x;
  unsigned r = c.u + 0x7FFFu + ((c.u >> 16) & 1u);
  return (unsigned short)(r >> 16);
}
__device__ __forceinline__ float bf2f(unsigned short v) {
  union { unsigned u; float f; } c; c.u = ((unsigned)v) << 16; return c.f;
}

// ---------------------------------------------------------------------------
// scan_sort_kernel: single block, LDS-staged. offs[N+1] = exclusive scan;
// sorted[] = segment ids by ascending size (counting sort).
// ---------------------------------------------------------------------------
__global__ __launch_bounds__(256) void scan_sort_kernel(
    const int* __restrict__ sizes, int* __restrict__ offs,
    int* __restrict__ sorted) {
  extern __shared__ int dynS[];      // 2 * NSEG ints
  int* szS = dynS;
  int* tmpS = dynS + NSEG;
  __shared__ int sums[256];
  __shared__ int bins[1024];
  const int t = threadIdx.x;

  for (int i = t; i < NSEG; i += 256) szS[i] = sizes[i];
  for (int i = t; i < 1024; i += 256) bins[i] = 0;
  __syncthreads();

  const int chunk = (NSEG + 255) >> 8;
  const int s0 = t * chunk, s1 = min(s0 + chunk, NSEG);
  int s = 0;
  for (int i = s0; i < s1; ++i) s += szS[i];
  sums[t] = s;
  __syncthreads();
  for (int d = 1; d < 256; d <<= 1) {
    int u = (t >= d) ? sums[t - d] : 0;
    __syncthreads();
    sums[t] += u;
    __syncthreads();
  }
  int a = sums[t] - s;
  for (int i = s0; i < s1; ++i) { tmpS[i] = a; a += szS[i]; }
  __syncthreads();
  for (int i = t; i < NSEG; i += 256) offs[i] = tmpS[i];
  if (t == 255) offs[NSEG] = a;

  for (int i = t; i < NSEG; i += 256) {
    int sz = szS[i]; sz = sz < 0 ? 0 : (sz > 1023 ? 1023 : sz);
    atomicAdd(&bins[sz], 1);
  }
  __syncthreads();
  const int c0 = bins[t * 4], c1 = bins[t * 4 + 1];
  const int c2 = bins[t * 4 + 2], c3 = bins[t * 4 + 3];
  const int loc = c0 + c1 + c2 + c3;
  sums[t] = loc;
  __syncthreads();
  for (int d = 1; d < 256; d <<= 1) {
    int u = (t >= d) ? sums[t - d] : 0;
    __syncthreads();
    sums[t] += u;
    __syncthreads();
  }
  const int base = sums[t] - loc;
  bins[t * 4]     = base;
  bins[t * 4 + 1] = base + c0;
  bins[t * 4 + 2] = base + c0 + c1;
  bins[t * 4 + 3] = base + c0 + c1 + c2;
  __syncthreads();
  for (int i = t; i < NSEG; i += 256) {
    int sz = szS[i]; sz = sz < 0 ? 0 : (sz > 1023 ? 1023 : sz);
    int pos = atomicAdd(&bins[sz], 1);
    tmpS[pos] = i;
  }
  __syncthreads();
  for (int i = t; i < NSEG; i += 256) sorted[i] = tmpS[i];
}

// ---------------------------------------------------------------------------
// Packers (x8 vectorized, one s16x8 store per thread).
// 16x16 B-frag (PWo/PW1m/PfW1): out[(g*N+n)*8+i] = W[(rowBase+g*8+i)*ld+n]
// ---------------------------------------------------------------------------
__device__ __forceinline__ void packB8(short* out, int idx8, const float* W,
                                       int N, int ld, int ncols, int kLimit,
                                       int rowBase) {
  const int n = (idx8 >> 3) % N;
  const int g = idx8 / (8 * N);
  s16x8 o;
#pragma unroll
  for (int i = 0; i < 8; ++i) {
    const int row = g * 8 + i;
    float v = 0.f;
    if (row < kLimit && n < ncols) v = W[(long)(rowBase + row) * ld + n];
    o[i] = (short)f2bf(v);
  }
  *(s16x8*)(out + idx8) = o;
}

// 32x32x16 A-operand pack of W1n^T: blk = Mblk*10+ks; lane holds
// A[m = Mblk*32 + (lane&31)][k = ks*16 + (lane>>5)*8 + i] = W1[k][m] (0 pad)
__device__ __forceinline__ void packA1T8(short* out, int idx8, const float* W1) {
  const int unit = idx8 >> 3;          // 0..2559
  const int lane = unit & 63;
  const int blk = unit >> 6;           // 0..39
  const int Mblk = blk / 10, ks = blk % 10;
  const int m = Mblk * 32 + (lane & 31);
  const int k0 = ks * 16 + ((lane >> 5) << 3);
  s16x8 o;
#pragma unroll
  for (int i = 0; i < 8; ++i) {
    const int k = k0 + i;
    o[i] = (short)((k < DD) ? f2bf(W1[(long)k * HH + m]) : 0);
  }
  *(s16x8*)(out + idx8) = o;
}

// 32x32x16 B-operand pack of W2: blk = ks*4+nb; lane holds
// B[k = ks*16 + (lane>>5)*8 + i][n = nb*32 + (lane&31)] = W2[k][n]
__device__ __forceinline__ void packB2T8(short* out, int idx8, const float* W2) {
  const int unit = idx8 >> 3;
  const int lane = unit & 63;
  const int blk = unit >> 6;           // 0..31
  const int ks = blk >> 2, nb = blk & 3;
  const int n = nb * 32 + (lane & 31);
  const int k0 = ks * 16 + ((lane >> 5) << 3);
  s16x8 o;
#pragma unroll
  for (int i = 0; i < 8; ++i)
    o[i] = (short)f2bf(W2[(long)(k0 + i) * HH + n]);
  *(s16x8*)(out + idx8) = o;
}

// ---------------------------------------------------------------------------
// pack_tab_kernel: weight packing + bf16 node table (stride 160, zero pad).
// ---------------------------------------------------------------------------
#define PACK_IDS 161792  // 40960+32768+36864+40960+10240
#define TAB_IDS (NSEG * 160)
#define PACKV (PACK_IDS / 8)  // 20224
#define TABV (TAB_IDS / 8)    // 317440
__global__ __launch_bounds__(256) void pack_tab_kernel(
    const float* __restrict__ interp, unsigned short* __restrict__ tab,
    const float* __restrict__ W1b0, const float* __restrict__ W1b1,
    const float* __restrict__ W2b0, const float* __restrict__ W2b1,
    const float* __restrict__ Wob0, const float* __restrict__ Wob1,
    const float* __restrict__ fW1, short* __restrict__ PA1,
    short* __restrict__ PB2, short* __restrict__ PWo,
    short* __restrict__ PW1m, short* __restrict__ PfW1) {
  int vid = blockIdx.x * 256 + threadIdx.x;
  if (vid < PACKV) {
    int idx = vid * 8;
    if (idx < 40960) {  // W1n^T A-frags (32x32x16), K 129->160, M 128
      packA1T8(PA1 + (idx / 20480) * 20480, idx % 20480,
               (idx < 20480) ? W1b0 : W1b1);
      return;
    }
    idx -= 40960;
    if (idx < 32768) {  // W2 B-frags (32x32x16), K 128, N 128
      packB2T8(PB2 + (idx / 16384) * 16384, idx % 16384,
               (idx < 16384) ? W2b0 : W2b1);
      return;
    }
    idx -= 32768;
    if (idx < 36864) {  // Wo (16x16), K 128, N 129->144
      packB8(PWo + (idx / 18432) * 18432, idx % 18432,
             (idx < 18432) ? Wob0 : Wob1, 144, 129, 129, 128, 0);
      return;
    }
    idx -= 36864;
    if (idx < 40960) {  // W1 main half (16x16, rows 129..257), K 129->160
      packB8(PW1m + (idx / 20480) * 20480, idx % 20480,
             (idx < 20480) ? W1b0 : W1b1, 128, 128, 128, 129, 129);
      return;
    }
    idx -= 40960;
    packB8(PfW1, idx, fW1, 64, 64, 64, 129, 0);  // fW1 (16x16) K 129->160
    return;
  }
  vid -= PACKV;
  if (vid < TABV) {
    const int n = vid / 20;
    const int g = vid - n * 20;
    s16x8 o = (s16x8){0, 0, 0, 0, 0, 0, 0, 0};
    if (g < 16) {
      const float* src = interp + (long)n * DD + g * 8;
#pragma unroll
      for (int i = 0; i < 8; ++i) o[i] = (short)f2bf(src[i]);
    } else if (g == 16) {
      o[0] = (short)f2bf(interp[(long)n * DD + 128]);
    }
    *(s16x8*)(tab + (long)vid * 8) = o;
  }
}

// ---------------------------------------------------------------------------
// HM = b1 + tab @ W1main  (16x16 MFMA over 16-node tiles; block-0 only)
// ---------------------------------------------------------------------------
__global__ __launch_bounds__(256) void hmprep_kernel(
    const unsigned short* __restrict__ tab, const short* __restrict__ PW1m,
    const float* __restrict__ b1, float* __restrict__ Hm) {
  const int lane = threadIdx.x & 63, w = threadIdx.x >> 6;
  const int lk = lane >> 4, n16 = lane & 15;
  const int tile = blockIdx.x * 4 + w;
  const unsigned short* arow = tab + (long)(tile * 16 + n16) * 160;
  s16x8 A[5];
#pragma unroll
  for (int ks = 0; ks < 5; ++ks) A[ks] = *(const s16x8*)(arow + ks * 32 + lk * 8);
  f32x4 C[8];
#pragma unroll
  for (int nf = 0; nf < 8; ++nf) C[nf] = (f32x4){0.f, 0.f, 0.f, 0.f};
#pragma unroll
  for (int ks = 0; ks < 5; ++ks)
#pragma unroll
    for (int nf = 0; nf < 8; ++nf) {
      const s16x8 b = *(const s16x8*)(PW1m + (((ks * 4 + lk) * 128) + nf * 16 + n16) * 8);
      C[nf] = __builtin_amdgcn_mfma_f32_16x16x32_bf16(A[ks], b, C[nf], 0, 0, 0);
    }
#pragma unroll
  for (int nf = 0; nf < 8; ++nf) {
    const float bv = b1[nf * 16 + n16];
#pragma unroll
    for (int r = 0; r < 4; ++r)
      Hm[(long)(tile * 16 + lk * 4 + r) * HH + nf * 16 + n16] = C[nf][r] + bv;
  }
}

// row within a packed pair -> edge index (rows < sLo from Lo segment, rest
// from Hi; overflow rows clamp to Hi's last edge — benign under max)
__device__ __forceinline__ int pairEdge(int row, int oLo, int sLo, int oHi,
                                        int sHi) {
  int e = (row < sLo) ? (oLo + row) : (oHi + row - sLo);
  if (row >= sLo + sHi) e = oHi + sHi - 1;
  return e;
}

// ---------------------------------------------------------------------------
// edge_kernel (32x32x16 MFMA): one segment PAIR = one 32-edge M-tile.
//  GEMM1: H1^T = W1n^T (A, LDS) x X^T (B, gathered b128 straight from TAB)
//         + bias MFMA (hm hi/lo x segment indicators + wv x iou).
//  D(col=edge,row=feat) -> relu -> b64 bounce into row-major H1[edge][feat].
//  GEMM2: C2 = H1 (A, b128 bounce reads shared over N-blocks) x W2 (B, LDS).
//  Pool: in-register masked max over D rows (=edges) + shfl_xor(32);
//        relu(max + b2) commutes with max.
// LDS ops/pair: 80 b128 + 16 b64 (vs 176 b128 of the 16x16 2-slot scheme).
// ---------------------------------------------------------------------------
__global__ __launch_bounds__(512, 2) void edge_kernel(
    const unsigned short* __restrict__ tab, const short* __restrict__ PA1,
    const short* __restrict__ PB2, const float* __restrict__ W1,
    const float* __restrict__ Hm, const float* __restrict__ iou,
    const int* __restrict__ nbrIdx, const int* __restrict__ offs,
    const int* __restrict__ sorted, const float* __restrict__ b2,
    unsigned short* __restrict__ pooled) {
  extern __shared__ __align__(16) char smem[];
  short* As1 = (short*)smem;               // 40960 B
  short* Bs2 = (short*)(smem + 40960);     // 32768 B
  short* bnc = (short*)(smem + 73728);     // 8 waves * 32*144*2 = 73728 B
  {
    const f32x4* s1 = (const f32x4*)PA1;
    f32x4* d1 = (f32x4*)As1;
    for (int i = threadIdx.x; i < 2560; i += 512) d1[i] = s1[i];
    const f32x4* s2 = (const f32x4*)PB2;
    f32x4* d2 = (f32x4*)Bs2;
    for (int i = threadIdx.x; i < 2048; i += 512) d2[i] = s2[i];
  }
  __syncthreads();

  const int lane = threadIdx.x & 63;
  const int w = threadIdx.x >> 6;
  const int half = lane >> 5, n32 = lane & 31;
  short* bw = bnc + w * (32 * 144);

  float b2v[4], wvT[4];
#pragma unroll
  for (int q = 0; q < 4; ++q) {
    b2v[q] = b2[q * 32 + n32];
    wvT[q] = W1[258 * HH + q * 32 + n32];
  }

  const int wid = (blockIdx.x << 3) + w;
  const int nw = gridDim.x << 3;
  const int npairs = NSEG >> 1;
  const short oneBf = (short)0x3F80;

  for (int p = wid; p < npairs; p += nw) {
    const int segLo = sorted[p], segHi = sorted[NSEG - 1 - p];
    const int oLo = offs[segLo], sLo = offs[segLo + 1] - oLo;
    const int oHi = offs[segHi], sHi = offs[segHi + 1] - oHi;
    const int nchunk = (sLo + sHi + 31) >> 5;

    float mxLo[4], mxHi[4];
#pragma unroll
    for (int q = 0; q < 4; ++q) { mxLo[q] = -3.4e38f; mxHi[q] = -3.4e38f; }

    for (int c = 0; c < nchunk; ++c) {
      const int grow = (c << 5) + n32;
      const int e = pairEdge(grow, oLo, sLo, oHi, sHi);
      const unsigned short* ar = tab + (long)nbrIdx[e] * 160;
      s16x8 X[10];
#pragma unroll
      for (int ks = 0; ks < 10; ++ks)
        X[ks] = *(const s16x8*)(ar + ks * 16 + half * 8);
      const float io = iou[e];
      // bias B-frag: k0,1 = indLo (pairs hm-Lo hi/lo), k2,3 = indHi, k4 = iou
      s16x8 bb = (s16x8){0, 0, 0, 0, 0, 0, 0, 0};
      if (half == 0) {
        const bool lo = grow < sLo;
        bb[0] = lo ? oneBf : (short)0;
        bb[1] = bb[0];
        bb[2] = lo ? (short)0 : oneBf;
        bb[3] = bb[2];
        bb[4] = (short)f2bf(io);
      }

      // GEMM1 + bias + bounce, per M-block (16 live C regs)
#pragma unroll
      for (int Mblk = 0; Mblk < 4; ++Mblk) {
        f32x16 C;
#pragma unroll
        for (int i = 0; i < 16; ++i) C[i] = 0.f;
#pragma unroll
        for (int ks = 0; ks < 10; ++ks) {
          const s16x8 a = *(const s16x8*)(As1 + ((Mblk * 10 + ks) * 64 + lane) * 8);
          C = __builtin_amdgcn_mfma_f32_32x32x16_bf16(a, X[ks], C, 0, 0, 0);
        }
        const float hLo = Hm[(long)segLo * HH + Mblk * 32 + n32];
        const float hHi = Hm[(long)segHi * HH + Mblk * 32 + n32];
        s16x8 ab = (s16x8){0, 0, 0, 0, 0, 0, 0, 0};
        if (half == 0) {
          const unsigned short p0 = f2bf(hLo);
          ab[0] = (short)p0;
          ab[1] = (short)f2bf(hLo - bf2f(p0));
          const unsigned short p1 = f2bf(hHi);
          ab[2] = (short)p1;
          ab[3] = (short)f2bf(hHi - bf2f(p1));
          ab[4] = (short)f2bf(wvT[Mblk]);
        }
        C = __builtin_amdgcn_mfma_f32_32x32x16_bf16(ab, bb, C, 0, 0, 0);
        // relu + pack: regs 4g+j -> feature Mblk*32 + 8g + 4*half + j
#pragma unroll
        for (int g = 0; g < 4; ++g) {
          s16x4 o;
#pragma unroll
          for (int j = 0; j < 4; ++j)
            o[j] = (short)f2bf(fmaxf(C[4 * g + j], 0.f));
          *(s16x4*)(bw + n32 * 144 + Mblk * 32 + 8 * g + 4 * half) = o;
        }
      }

      // GEMM2: A2 rows from bounce (8 reads, shared over 4 N-blocks)
      s16x8 A2[8];
#pragma unroll
      for (int ks = 0; ks < 8; ++ks)
        A2[ks] = *(const s16x8*)(bw + n32 * 144 + ks * 16 + half * 8);
#pragma unroll
      for (int nb = 0; nb < 4; ++nb) {
        f32x16 D;
#pragma unroll
        for (int i = 0; i < 16; ++i) D[i] = 0.f;
#pragma unroll
        for (int ks = 0; ks < 8; ++ks) {
          const s16x8 b = *(const s16x8*)(Bs2 + ((ks * 4 + nb) * 64 + lane) * 8);
          D = __builtin_amdgcn_mfma_f32_32x32x16_bf16(A2[ks], b, D, 0, 0, 0);
        }
        // masked max over edge rows (clamped rows duplicate Hi's last edge)
#pragma unroll
        for (int reg = 0; reg < 16; ++reg) {
          const int rrow = (reg & 3) + 8 * (reg >> 2) + 4 * half;
          const int gr = (c << 5) + rrow;
          const float v = D[reg];
          if (gr < sLo) mxLo[nb] = fmaxf(mxLo[nb], v);
          else          mxHi[nb] = fmaxf(mxHi[nb], v);
        }
      }
    }
    // merge halves + store pooled = relu(max + b2)
#pragma unroll
    for (int nb = 0; nb < 4; ++nb) {
      float lo = fmaxf(mxLo[nb], __shfl_xor(mxLo[nb], 32, 64));
      float hi = fmaxf(mxHi[nb], __shfl_xor(mxHi[nb], 32, 64));
      if (half == 0) {
        pooled[(long)segLo * HH + nb * 32 + n32] = f2bf(fmaxf(lo + b2v[nb], 0.f));
        pooled[(long)segHi * HH + nb * 32 + n32] = f2bf(fmaxf(hi + b2v[nb], 0.f));
      }
    }
  }
}

// ---------------------------------------------------------------------------
// resout: RES = resIn + bo + pooled @ Wo (16x16 MFMA). Then via bf16 bounce:
//   NEXT=1: write resOut fp32 + TAB bf16 and compute HM_next = b1n + res@W1m.
//   NEXT=0: fused final head out = relu(res@fW1+fb1)@fW2 + fb2.
// ---------------------------------------------------------------------------
template <int NEXT>
__global__ __launch_bounds__(256) void resout_kernel(
    const unsigned short* __restrict__ pooled, const short* __restrict__ PWo,
    const float* __restrict__ bo, const float* __restrict__ resIn,
    float* __restrict__ resOut, unsigned short* __restrict__ tab,
    const short* __restrict__ PW1mN, const float* __restrict__ b1n,
    float* __restrict__ HmOut,
    const short* __restrict__ PfW1, const float* __restrict__ fb1,
    const float* __restrict__ fW2, const float* __restrict__ fb2,
    float* __restrict__ outFinal) {
  __shared__ short stS[4][16 * 168];
  const int lane = threadIdx.x & 63, w = threadIdx.x >> 6;
  const int lk = lane >> 4, n16 = lane & 15;
  short* st = stS[w];

  {
    const int row = lane >> 2, c0 = 129 + (lane & 3) * 8;
#pragma unroll
    for (int i = 0; i < 8; ++i) st[row * 168 + c0 + i] = 0;
  }

  const int tile = blockIdx.x * 4 + w;
  const unsigned short* arow = pooled + (long)(tile * 16 + n16) * HH;
  s16x8 A[4];
#pragma unroll
  for (int ks = 0; ks < 4; ++ks) A[ks] = *(const s16x8*)(arow + ks * 32 + lk * 8);
  f32x4 C[9];
#pragma unroll
  for (int nf = 0; nf < 9; ++nf) C[nf] = (f32x4){0.f, 0.f, 0.f, 0.f};
#pragma unroll
  for (int ks = 0; ks < 4; ++ks)
#pragma unroll
    for (int nf = 0; nf < 9; ++nf) {
      const s16x8 b = *(const s16x8*)(PWo + (((ks * 4 + lk) * 144) + nf * 16 + n16) * 8);
      C[nf] = __builtin_amdgcn_mfma_f32_16x16x32_bf16(A[ks], b, C[nf], 0, 0, 0);
    }

#pragma unroll
  for (int nf = 0; nf < 8; ++nf) {
    const int col = nf * 16 + n16;
    const float bov = bo[col];
#pragma unroll
    for (int r = 0; r < 4; ++r) {
      const int row = lk * 4 + r;
      const long node = tile * 16 + row;
      const float res = resIn[node * DD + col] + bov + C[nf][r];
      if (NEXT) {
        resOut[node * DD + col] = res;
        tab[node * 160 + col] = f2bf(res);
      }
      st[row * 168 + col] = (short)f2bf(res);
    }
  }
  if (n16 == 0) {
#pragma unroll
    for (int r = 0; r < 4; ++r) {
      const int row = lk * 4 + r;
      const long node = tile * 16 + row;
      const float res = resIn[node * DD + 128] + bo[128] + C[8][r];
      if (NEXT) {
        resOut[node * DD + 128] = res;
        tab[node * 160 + 128] = f2bf(res);
      }
      st[row * 168 + 128] = (short)f2bf(res);
    }
  }

  s16x8 A5[5];
#pragma unroll
  for (int ks = 0; ks < 5; ++ks)
    A5[ks] = *(const s16x8*)(st + n16 * 168 + ks * 32 + lk * 8);

  if (NEXT) {
    f32x4 H[8];
#pragma unroll
    for (int nf = 0; nf < 8; ++nf) H[nf] = (f32x4){0.f, 0.f, 0.f, 0.f};
#pragma unroll
    for (int ks = 0; ks < 5; ++ks)
#pragma unroll
      for (int nf = 0; nf < 8; ++nf) {
        const s16x8 b = *(const s16x8*)(PW1mN + (((ks * 4 + lk) * 128) + nf * 16 + n16) * 8);
        H[nf] = __builtin_amdgcn_mfma_f32_16x16x32_bf16(A5[ks], b, H[nf], 0, 0, 0);
      }
#pragma unroll
    for (int nf = 0; nf < 8; ++nf) {
      const float bv = b1n[nf * 16 + n16];
#pragma unroll
      for (int r = 0; r < 4; ++r)
        HmOut[(long)(tile * 16 + lk * 4 + r) * HH + nf * 16 + n16] = H[nf][r] + bv;
    }
  } else {
    f32x4 Ch[4];
#pragma unroll
    for (int nf = 0; nf < 4; ++nf) Ch[nf] = (f32x4){0.f, 0.f, 0.f, 0.f};
#pragma unroll
    for (int ks = 0; ks < 5; ++ks)
#pragma unroll
      for (int nf = 0; nf < 4; ++nf) {
        const s16x8 b = *(const s16x8*)(PfW1 + (((ks * 4 + lk) * 64) + nf * 16 + n16) * 8);
        Ch[nf] = __builtin_amdgcn_mfma_f32_16x16x32_bf16(A5[ks], b, Ch[nf], 0, 0, 0);
      }
    float b1v[4], w2v[4];
#pragma unroll
    for (int nf = 0; nf < 4; ++nf) {
      b1v[nf] = fb1[nf * 16 + n16];
      w2v[nf] = fW2[nf * 16 + n16];
    }
#pragma unroll
    for (int r = 0; r < 4; ++r) {
      float s = 0.f;
#pragma unroll
      for (int nf = 0; nf < 4; ++nf)
        s += fmaxf(Ch[nf][r] + b1v[nf], 0.f) * w2v[nf];
      s += __shfl_xor(s, 1, 64);
      s += __shfl_xor(s, 2, 64);
      s += __shfl_xor(s, 4, 64);
      s += __shfl_xor(s, 8, 64);
      if (n16 == 0) outFinal[tile * 16 + lk * 4 + r] = s + fb2[0];
    }
  }
}

// ---------------------------------------------------------------------------
extern "C" void kernel_launch(void* const* d_in, const int* in_sizes, int n_in,
                              void* d_out, int out_size, void* d_ws, size_t ws_size,
                              hipStream_t stream) {
  const float* interp  = (const float*)d_in[0];
  const float* addInfo = (const float*)d_in[1];
  const int* sizes     = (const int*)d_in[2];
  const int* nbrIdx    = (const int*)d_in[3];
  const float* b0W1 = (const float*)d_in[5];
  const float* b0b1 = (const float*)d_in[6];
  const float* b0W2 = (const float*)d_in[7];
  const float* b0b2 = (const float*)d_in[8];
  const float* b0Wo = (const float*)d_in[9];
  const float* b0bo = (const float*)d_in[10];
  const float* b1W1 = (const float*)d_in[11];
  const float* b1b1 = (const float*)d_in[12];
  const float* b1W2 = (const float*)d_in[13];
  const float* b1b2 = (const float*)d_in[14];
  const float* b1Wo = (const float*)d_in[15];
  const float* b1bo = (const float*)d_in[16];
  const float* fW1  = (const float*)d_in[17];
  const float* fb1  = (const float*)d_in[18];
  const float* fW2  = (const float*)d_in[19];
  const float* fb2  = (const float*)d_in[20];

  char* ws = (char*)d_ws;
  int*            offs  = (int*)(ws + 0);                    // 65536
  short*          PA1   = (short*)(ws + 65536);              // 81920
  short*          PB2   = (short*)(ws + 147456);             // 65536
  short*          PWo   = (short*)(ws + 212992);             // 73728
  short*          PW1m  = (short*)(ws + 286720);             // 81920
  short*          PfW1  = (short*)(ws + 368640);             // 20480 -> pad
  unsigned short* TAB   = (unsigned short*)(ws + 393216);    // N*160*2
  float*          HM    = (float*)(ws + 5472256);            // N*128*4
  unsigned short* POOLED= (unsigned short*)(ws + 13598720);  // N*128*2
  float*          RES   = (float*)(ws + 17661952);           // N*129*4
  int*            SORTED= (int*)(ws + 25851904);             // N*4

  scan_sort_kernel<<<1, 256, 2 * NSEG * sizeof(int), stream>>>(sizes, offs,
                                                               SORTED);
  pack_tab_kernel<<<(PACKV + TABV) / 256, 256, 0, stream>>>(
      interp, TAB, b0W1, b1W1, b0W2, b1W2, b0Wo, b1Wo, fW1,
      PA1, PB2, PWo, PW1m, PfW1);

  const size_t e_lds = 40960 + 32768 + 8 * 32 * 144 * 2;  // 147456

  // ---- block 0 ----
  hmprep_kernel<<<NTILE / 4, 256, 0, stream>>>(TAB, PW1m, b0b1, HM);
  edge_kernel<<<256, 512, e_lds, stream>>>(TAB, PA1, PB2, b0W1, HM, addInfo,
                                           nbrIdx, offs, SORTED, b0b2, POOLED);
  resout_kernel<1><<<NTILE / 4, 256, 0, stream>>>(
      POOLED, PWo, b0bo, interp, RES, TAB, PW1m + 20480, b1b1, HM,
      nullptr, nullptr, nullptr, nullptr, nullptr);

  // ---- block 1 ----
  edge_kernel<<<256, 512, e_lds, stream>>>(TAB, PA1 + 20480, PB2 + 16384, b1W1,
                                           HM, addInfo, nbrIdx, offs, SORTED,
                                           b1b2, POOLED);
  resout_kernel<0><<<NTILE / 4, 256, 0, stream>>>(
      POOLED, PWo + 18432, b1bo, RES, nullptr, nullptr, nullptr, nullptr,
      nullptr, PfW1, fb1, fW2, fb2, (float*)d_out);
}

// Round 14
// 206.674 us; speedup vs baseline: 1.0694x; 1.0694x over previous
//
#include <hip/hip_runtime.h>

#define NSEG 15872
#define DD 129
#define HH 128
#define NTILE (NSEG / 16)  // 992 node tiles

typedef __attribute__((ext_vector_type(8))) short s16x8;
typedef __attribute__((ext_vector_type(4))) short s16x4;
typedef __attribute__((ext_vector_type(4))) float f32x4;
typedef __attribute__((ext_vector_type(16))) float f32x16;

__device__ __forceinline__ unsigned short f2bf(float x) {
  union { float f; unsigned u; } c; c.f = x;
  unsigned r = c.u + 0x7FFFu + ((c.u >> 16) & 1u);
  return (unsigned short)(r >> 16);
}
__device__ __forceinline__ float bf2f(unsigned short v) {
  union { unsigned u; float f; } c; c.u = ((unsigned)v) << 16; return c.f;
}

// ---------------------------------------------------------------------------
// scan_sort_kernel: single block, LDS-staged. offs[N+1] = exclusive scan;
// sorted[] = segment ids by ascending size (counting sort).
// ---------------------------------------------------------------------------
__global__ __launch_bounds__(256) void scan_sort_kernel(
    const int* __restrict__ sizes, int* __restrict__ offs,
    int* __restrict__ sorted) {
  extern __shared__ int dynS[];      // 2 * NSEG ints
  int* szS = dynS;
  int* tmpS = dynS + NSEG;
  __shared__ int sums[256];
  __shared__ int bins[1024];
  const int t = threadIdx.x;

  for (int i = t; i < NSEG; i += 256) szS[i] = sizes[i];
  for (int i = t; i < 1024; i += 256) bins[i] = 0;
  __syncthreads();

  const int chunk = (NSEG + 255) >> 8;
  const int s0 = t * chunk, s1 = min(s0 + chunk, NSEG);
  int s = 0;
  for (int i = s0; i < s1; ++i) s += szS[i];
  sums[t] = s;
  __syncthreads();
  for (int d = 1; d < 256; d <<= 1) {
    int u = (t >= d) ? sums[t - d] : 0;
    __syncthreads();
    sums[t] += u;
    __syncthreads();
  }
  int a = sums[t] - s;
  for (int i = s0; i < s1; ++i) { tmpS[i] = a; a += szS[i]; }
  __syncthreads();
  for (int i = t; i < NSEG; i += 256) offs[i] = tmpS[i];
  if (t == 255) offs[NSEG] = a;

  for (int i = t; i < NSEG; i += 256) {
    int sz = szS[i]; sz = sz < 0 ? 0 : (sz > 1023 ? 1023 : sz);
    atomicAdd(&bins[sz], 1);
  }
  __syncthreads();
  const int c0 = bins[t * 4], c1 = bins[t * 4 + 1];
  const int c2 = bins[t * 4 + 2], c3 = bins[t * 4 + 3];
  const int loc = c0 + c1 + c2 + c3;
  sums[t] = loc;
  __syncthreads();
  for (int d = 1; d < 256; d <<= 1) {
    int u = (t >= d) ? sums[t - d] : 0;
    __syncthreads();
    sums[t] += u;
    __syncthreads();
  }
  const int base = sums[t] - loc;
  bins[t * 4]     = base;
  bins[t * 4 + 1] = base + c0;
  bins[t * 4 + 2] = base + c0 + c1;
  bins[t * 4 + 3] = base + c0 + c1 + c2;
  __syncthreads();
  for (int i = t; i < NSEG; i += 256) {
    int sz = szS[i]; sz = sz < 0 ? 0 : (sz > 1023 ? 1023 : sz);
    int pos = atomicAdd(&bins[sz], 1);
    tmpS[pos] = i;
  }
  __syncthreads();
  for (int i = t; i < NSEG; i += 256) sorted[i] = tmpS[i];
}

// ---------------------------------------------------------------------------
// Packers (x8 vectorized, one s16x8 store per thread).
// ---------------------------------------------------------------------------
__device__ __forceinline__ void packB8(short* out, int idx8, const float* W,
                                       int N, int ld, int ncols, int kLimit,
                                       int rowBase) {
  const int n = (idx8 >> 3) % N;
  const int g = idx8 / (8 * N);
  s16x8 o;
#pragma unroll
  for (int i = 0; i < 8; ++i) {
    const int row = g * 8 + i;
    float v = 0.f;
    if (row < kLimit && n < ncols) v = W[(long)(rowBase + row) * ld + n];
    o[i] = (short)f2bf(v);
  }
  *(s16x8*)(out + idx8) = o;
}

// 32x32x16 A-operand pack of W1n^T: blk = Mblk*10+ks; lane holds
// A[m = Mblk*32 + (lane&31)][k = ks*16 + (lane>>5)*8 + i] = W1[k][m] (0 pad)
__device__ __forceinline__ void packA1T8(short* out, int idx8, const float* W1) {
  const int unit = idx8 >> 3;          // 0..2559
  const int lane = unit & 63;
  const int blk = unit >> 6;           // 0..39
  const int Mblk = blk / 10, ks = blk % 10;
  const int m = Mblk * 32 + (lane & 31);
  const int k0 = ks * 16 + ((lane >> 5) << 3);
  s16x8 o;
#pragma unroll
  for (int i = 0; i < 8; ++i) {
    const int k = k0 + i;
    o[i] = (short)((k < DD) ? f2bf(W1[(long)k * HH + m]) : 0);
  }
  *(s16x8*)(out + idx8) = o;
}

// 32x32x16 B-operand pack of W2: blk = ks*4+nb; lane holds
// B[k = ks*16 + (lane>>5)*8 + i][n = nb*32 + (lane&31)] = W2[k][n]
__device__ __forceinline__ void packB2T8(short* out, int idx8, const float* W2) {
  const int unit = idx8 >> 3;
  const int lane = unit & 63;
  const int blk = unit >> 6;           // 0..31
  const int ks = blk >> 2, nb = blk & 3;
  const int n = nb * 32 + (lane & 31);
  const int k0 = ks * 16 + ((lane >> 5) << 3);
  s16x8 o;
#pragma unroll
  for (int i = 0; i < 8; ++i)
    o[i] = (short)f2bf(W2[(long)(k0 + i) * HH + n]);
  *(s16x8*)(out + idx8) = o;
}

// ---------------------------------------------------------------------------
// pack_tab_kernel: weight packing + bf16 node table (stride 160, zero pad).
// ---------------------------------------------------------------------------
#define PACK_IDS 161792  // 40960+32768+36864+40960+10240
#define TAB_IDS (NSEG * 160)
#define PACKV (PACK_IDS / 8)  // 20224
#define TABV (TAB_IDS / 8)    // 317440
__global__ __launch_bounds__(256) void pack_tab_kernel(
    const float* __restrict__ interp, unsigned short* __restrict__ tab,
    const float* __restrict__ W1b0, const float* __restrict__ W1b1,
    const float* __restrict__ W2b0, const float* __restrict__ W2b1,
    const float* __restrict__ Wob0, const float* __restrict__ Wob1,
    const float* __restrict__ fW1, short* __restrict__ PA1,
    short* __restrict__ PB2, short* __restrict__ PWo,
    short* __restrict__ PW1m, short* __restrict__ PfW1) {
  int vid = blockIdx.x * 256 + threadIdx.x;
  if (vid < PACKV) {
    int idx = vid * 8;
    if (idx < 40960) {  // W1n^T A-frags (32x32x16), K 129->160, M 128
      packA1T8(PA1 + (idx / 20480) * 20480, idx % 20480,
               (idx < 20480) ? W1b0 : W1b1);
      return;
    }
    idx -= 40960;
    if (idx < 32768) {  // W2 B-frags (32x32x16), K 128, N 128
      packB2T8(PB2 + (idx / 16384) * 16384, idx % 16384,
               (idx < 16384) ? W2b0 : W2b1);
      return;
    }
    idx -= 32768;
    if (idx < 36864) {  // Wo (16x16), K 128, N 129->144
      packB8(PWo + (idx / 18432) * 18432, idx % 18432,
             (idx < 18432) ? Wob0 : Wob1, 144, 129, 129, 128, 0);
      return;
    }
    idx -= 36864;
    if (idx < 40960) {  // W1 main half (16x16, rows 129..257), K 129->160
      packB8(PW1m + (idx / 20480) * 20480, idx % 20480,
             (idx < 20480) ? W1b0 : W1b1, 128, 128, 128, 129, 129);
      return;
    }
    idx -= 40960;
    packB8(PfW1, idx, fW1, 64, 64, 64, 129, 0);  // fW1 (16x16) K 129->160
    return;
  }
  vid -= PACKV;
  if (vid < TABV) {
    const int n = vid / 20;
    const int g = vid - n * 20;
    s16x8 o = (s16x8){0, 0, 0, 0, 0, 0, 0, 0};
    if (g < 16) {
      const float* src = interp + (long)n * DD + g * 8;
#pragma unroll
      for (int i = 0; i < 8; ++i) o[i] = (short)f2bf(src[i]);
    } else if (g == 16) {
      o[0] = (short)f2bf(interp[(long)n * DD + 128]);
    }
    *(s16x8*)(tab + (long)vid * 8) = o;
  }
}

// ---------------------------------------------------------------------------
// HM = b1 + tab @ W1main  (16x16 MFMA over 16-node tiles; block-0 only)
// ---------------------------------------------------------------------------
__global__ __launch_bounds__(256) void hmprep_kernel(
    const unsigned short* __restrict__ tab, const short* __restrict__ PW1m,
    const float* __restrict__ b1, float* __restrict__ Hm) {
  const int lane = threadIdx.x & 63, w = threadIdx.x >> 6;
  const int lk = lane >> 4, n16 = lane & 15;
  const int tile = blockIdx.x * 4 + w;
  const unsigned short* arow = tab + (long)(tile * 16 + n16) * 160;
  s16x8 A[5];
#pragma unroll
  for (int ks = 0; ks < 5; ++ks) A[ks] = *(const s16x8*)(arow + ks * 32 + lk * 8);
  f32x4 C[8];
#pragma unroll
  for (int nf = 0; nf < 8; ++nf) C[nf] = (f32x4){0.f, 0.f, 0.f, 0.f};
#pragma unroll
  for (int ks = 0; ks < 5; ++ks)
#pragma unroll
    for (int nf = 0; nf < 8; ++nf) {
      const s16x8 b = *(const s16x8*)(PW1m + (((ks * 4 + lk) * 128) + nf * 16 + n16) * 8);
      C[nf] = __builtin_amdgcn_mfma_f32_16x16x32_bf16(A[ks], b, C[nf], 0, 0, 0);
    }
#pragma unroll
  for (int nf = 0; nf < 8; ++nf) {
    const float bv = b1[nf * 16 + n16];
#pragma unroll
    for (int r = 0; r < 4; ++r)
      Hm[(long)(tile * 16 + lk * 4 + r) * HH + nf * 16 + n16] = C[nf][r] + bv;
  }
}

// row within a packed pair -> edge index
__device__ __forceinline__ int pairEdge(int row, int oLo, int sLo, int oHi,
                                        int sHi) {
  int e = (row < sLo) ? (oLo + row) : (oHi + row - sLo);
  if (row >= sLo + sHi) e = oHi + sHi - 1;
  return e;
}

struct PairMeta {
  int segLo, segHi, oLo, sLo, oHi, sHi;
  float hmLo[4], hmHi[4];
};

__device__ __forceinline__ void loadMeta(
    int p, PairMeta& M, const int* __restrict__ sorted,
    const int* __restrict__ offs, const float* __restrict__ Hm, int n32) {
  M.segLo = sorted[p];
  M.segHi = sorted[NSEG - 1 - p];
  M.oLo = offs[M.segLo]; M.sLo = offs[M.segLo + 1] - M.oLo;
  M.oHi = offs[M.segHi]; M.sHi = offs[M.segHi + 1] - M.oHi;
#pragma unroll
  for (int q = 0; q < 4; ++q) {
    M.hmLo[q] = Hm[(long)M.segLo * HH + q * 32 + n32];
    M.hmHi[q] = Hm[(long)M.segHi * HH + q * 32 + n32];
  }
}

__device__ __forceinline__ void gatherX(
    const PairMeta& M, int c, const unsigned short* __restrict__ tab,
    const int* __restrict__ nbrIdx, const float* __restrict__ iou,
    int n32, int half, s16x8* X, float& io) {
  const int grow = (c << 5) + n32;
  const int e = pairEdge(grow, M.oLo, M.sLo, M.oHi, M.sHi);
  const unsigned short* ar = tab + (long)nbrIdx[e] * 160;
#pragma unroll
  for (int ks = 0; ks < 10; ++ks)
    X[ks] = *(const s16x8*)(ar + ks * 16 + half * 8);
  io = iou[e];
}

// GEMM1 + bias MFMA + relu + bounce write (row stride 136 shorts: 68 words
// = 4 mod 32 -> full bank coverage; 144 was 8 mod 32 = half banks, the R13
// 1.78M-conflict regression)
__device__ __forceinline__ void gemm1Phase(
    const PairMeta& M, int c, const s16x8* X, float io,
    const short* __restrict__ As1, short* bw, const float* wvT,
    int lane, int half, int n32) {
  const int grow = (c << 5) + n32;
  const short oneBf = (short)0x3F80;
  s16x8 bb = (s16x8){0, 0, 0, 0, 0, 0, 0, 0};
  if (half == 0) {
    const bool lo = grow < M.sLo;
    bb[0] = lo ? oneBf : (short)0;
    bb[1] = bb[0];
    bb[2] = lo ? (short)0 : oneBf;
    bb[3] = bb[2];
    bb[4] = (short)f2bf(io);
  }
#pragma unroll
  for (int Mblk = 0; Mblk < 4; ++Mblk) {
    f32x16 C;
#pragma unroll
    for (int i = 0; i < 16; ++i) C[i] = 0.f;
#pragma unroll
    for (int ks = 0; ks < 10; ++ks) {
      const s16x8 a = *(const s16x8*)(As1 + ((Mblk * 10 + ks) * 64 + lane) * 8);
      C = __builtin_amdgcn_mfma_f32_32x32x16_bf16(a, X[ks], C, 0, 0, 0);
    }
    s16x8 ab = (s16x8){0, 0, 0, 0, 0, 0, 0, 0};
    if (half == 0) {
      const unsigned short p0 = f2bf(M.hmLo[Mblk]);
      ab[0] = (short)p0;
      ab[1] = (short)f2bf(M.hmLo[Mblk] - bf2f(p0));
      const unsigned short p1 = f2bf(M.hmHi[Mblk]);
      ab[2] = (short)p1;
      ab[3] = (short)f2bf(M.hmHi[Mblk] - bf2f(p1));
      ab[4] = (short)f2bf(wvT[Mblk]);
    }
    C = __builtin_amdgcn_mfma_f32_32x32x16_bf16(ab, bb, C, 0, 0, 0);
#pragma unroll
    for (int g = 0; g < 4; ++g) {
      s16x4 o;
#pragma unroll
      for (int j = 0; j < 4; ++j)
        o[j] = (short)f2bf(fmaxf(C[4 * g + j], 0.f));
      *(s16x4*)(bw + n32 * 136 + Mblk * 32 + 8 * g + 4 * half) = o;
    }
  }
}

// GEMM2 + masked segment-split max update
__device__ __forceinline__ void gemm2Phase(
    const PairMeta& M, int c, const short* bw, const short* __restrict__ Bs2,
    int lane, int half, int n32, float* mxLo, float* mxHi) {
  s16x8 A2[8];
#pragma unroll
  for (int ks = 0; ks < 8; ++ks)
    A2[ks] = *(const s16x8*)(bw + n32 * 136 + ks * 16 + half * 8);
#pragma unroll
  for (int nb = 0; nb < 4; ++nb) {
    f32x16 D;
#pragma unroll
    for (int i = 0; i < 16; ++i) D[i] = 0.f;
#pragma unroll
    for (int ks = 0; ks < 8; ++ks) {
      const s16x8 b = *(const s16x8*)(Bs2 + ((ks * 4 + nb) * 64 + lane) * 8);
      D = __builtin_amdgcn_mfma_f32_32x32x16_bf16(A2[ks], b, D, 0, 0, 0);
    }
#pragma unroll
    for (int reg = 0; reg < 16; ++reg) {
      const int rrow = (reg & 3) + 8 * (reg >> 2) + 4 * half;
      const int gr = (c << 5) + rrow;
      const float v = D[reg];
      if (gr < M.sLo) mxLo[nb] = fmaxf(mxLo[nb], v);
      else            mxHi[nb] = fmaxf(mxHi[nb], v);
    }
  }
}

__device__ __forceinline__ void finishPair(
    const PairMeta& M, int c0done, const unsigned short* __restrict__ tab,
    const int* __restrict__ nbrIdx, const float* __restrict__ iou,
    const short* __restrict__ As1, const short* __restrict__ Bs2, short* bw,
    const float* wvT, const float* b2v, int lane, int half, int n32,
    float* mxLo, float* mxHi, unsigned short* __restrict__ pooled) {
  // rare multi-chunk fallback (pairs not summing to <=32 edges)
  const int nchunk = (M.sLo + M.sHi + 31) >> 5;
  for (int c = 1; c < nchunk; ++c) {
    s16x8 Xr[10];
    float ior;
    gatherX(M, c, tab, nbrIdx, iou, n32, half, Xr, ior);
    gemm1Phase(M, c, Xr, ior, As1, bw, wvT, lane, half, n32);
    gemm2Phase(M, c, bw, Bs2, lane, half, n32, mxLo, mxHi);
  }
#pragma unroll
  for (int nb = 0; nb < 4; ++nb) {
    float lo = fmaxf(mxLo[nb], __shfl_xor(mxLo[nb], 32, 64));
    float hi = fmaxf(mxHi[nb], __shfl_xor(mxHi[nb], 32, 64));
    if (half == 0) {
      pooled[(long)M.segLo * HH + nb * 32 + n32] = f2bf(fmaxf(lo + b2v[nb], 0.f));
      pooled[(long)M.segHi * HH + nb * 32 + n32] = f2bf(fmaxf(hi + b2v[nb], 0.f));
    }
  }
}

// ---------------------------------------------------------------------------
// edge_kernel (32x32x16 MFMA): one segment PAIR = one 32-edge M-tile, with
// cross-pair software pipelining: next pair's meta loads issue before this
// pair's GEMM1, next pair's X-gather issues between GEMM1 and GEMM2 (each
// L2 hop covered by ~1000 cyc of MFMA). Fixed A/B register buffers via
// 2x-unrolled loop (no spill-prone ternary refs).
// ---------------------------------------------------------------------------
__global__ __launch_bounds__(512, 2) void edge_kernel(
    const unsigned short* __restrict__ tab, const short* __restrict__ PA1,
    const short* __restrict__ PB2, const float* __restrict__ W1,
    const float* __restrict__ Hm, const float* __restrict__ iou,
    const int* __restrict__ nbrIdx, const int* __restrict__ offs,
    const int* __restrict__ sorted, const float* __restrict__ b2,
    unsigned short* __restrict__ pooled) {
  extern __shared__ __align__(16) char smem[];
  short* As1 = (short*)smem;               // 40960 B
  short* Bs2 = (short*)(smem + 40960);     // 32768 B
  short* bnc = (short*)(smem + 73728);     // 8 waves * 32*136*2 = 69632 B
  {
    const f32x4* s1 = (const f32x4*)PA1;
    f32x4* d1 = (f32x4*)As1;
    for (int i = threadIdx.x; i < 2560; i += 512) d1[i] = s1[i];
    const f32x4* s2 = (const f32x4*)PB2;
    f32x4* d2 = (f32x4*)Bs2;
    for (int i = threadIdx.x; i < 2048; i += 512) d2[i] = s2[i];
  }
  __syncthreads();

  const int lane = threadIdx.x & 63;
  const int w = threadIdx.x >> 6;
  const int half = lane >> 5, n32 = lane & 31;
  short* bw = bnc + w * (32 * 136);

  float b2v[4], wvT[4];
#pragma unroll
  for (int q = 0; q < 4; ++q) {
    b2v[q] = b2[q * 32 + n32];
    wvT[q] = W1[258 * HH + q * 32 + n32];
  }

  const int wid = (blockIdx.x << 3) + w;
  const int nw = gridDim.x << 3;
  const int npairs = NSEG >> 1;

  int p = wid;
  if (p < npairs) {
    PairMeta MA, MB;
    s16x8 XA[10], XB[10];
    float ioA, ioB;
    loadMeta(p, MA, sorted, offs, Hm, n32);
    gatherX(MA, 0, tab, nbrIdx, iou, n32, half, XA, ioA);
    for (;;) {
      // ---- pair p (A buffers) ----
      const int p1 = p + nw;
      const bool h1 = p1 < npairs;
      if (h1) loadMeta(p1, MB, sorted, offs, Hm, n32);
      float mxLo[4], mxHi[4];
#pragma unroll
      for (int q = 0; q < 4; ++q) { mxLo[q] = -3.4e38f; mxHi[q] = -3.4e38f; }
      gemm1Phase(MA, 0, XA, ioA, As1, bw, wvT, lane, half, n32);
      if (h1) gatherX(MB, 0, tab, nbrIdx, iou, n32, half, XB, ioB);
      gemm2Phase(MA, 0, bw, Bs2, lane, half, n32, mxLo, mxHi);
      finishPair(MA, 1, tab, nbrIdx, iou, As1, Bs2, bw, wvT, b2v, lane, half,
                 n32, mxLo, mxHi, pooled);
      if (!h1) break;
      // ---- pair p1 (B buffers) ----
      const int p2 = p1 + nw;
      const bool h2 = p2 < npairs;
      if (h2) loadMeta(p2, MA, sorted, offs, Hm, n32);
#pragma unroll
      for (int q = 0; q < 4; ++q) { mxLo[q] = -3.4e38f; mxHi[q] = -3.4e38f; }
      gemm1Phase(MB, 0, XB, ioB, As1, bw, wvT, lane, half, n32);
      if (h2) gatherX(MA, 0, tab, nbrIdx, iou, n32, half, XA, ioA);
      gemm2Phase(MB, 0, bw, Bs2, lane, half, n32, mxLo, mxHi);
      finishPair(MB, 1, tab, nbrIdx, iou, As1, Bs2, bw, wvT, b2v, lane, half,
                 n32, mxLo, mxHi, pooled);
      if (!h2) break;
      p = p2;
    }
  }
}

// ---------------------------------------------------------------------------
// resout: RES = resIn + bo + pooled @ Wo (16x16 MFMA). Then via bf16 bounce:
//   NEXT=1: write resOut fp32 + TAB bf16 and compute HM_next = b1n + res@W1m.
//   NEXT=0: fused final head out = relu(res@fW1+fb1)@fW2 + fb2.
// ---------------------------------------------------------------------------
template <int NEXT>
__global__ __launch_bounds__(256) void resout_kernel(
    const unsigned short* __restrict__ pooled, const short* __restrict__ PWo,
    const float* __restrict__ bo, const float* __restrict__ resIn,
    float* __restrict__ resOut, unsigned short* __restrict__ tab,
    const short* __restrict__ PW1mN, const float* __restrict__ b1n,
    float* __restrict__ HmOut,
    const short* __restrict__ PfW1, const float* __restrict__ fb1,
    const float* __restrict__ fW2, const float* __restrict__ fb2,
    float* __restrict__ outFinal) {
  __shared__ short stS[4][16 * 168];
  const int lane = threadIdx.x & 63, w = threadIdx.x >> 6;
  const int lk = lane >> 4, n16 = lane & 15;
  short* st = stS[w];

  {
    const int row = lane >> 2, c0 = 129 + (lane & 3) * 8;
#pragma unroll
    for (int i = 0; i < 8; ++i) st[row * 168 + c0 + i] = 0;
  }

  const int tile = blockIdx.x * 4 + w;
  const unsigned short* arow = pooled + (long)(tile * 16 + n16) * HH;
  s16x8 A[4];
#pragma unroll
  for (int ks = 0; ks < 4; ++ks) A[ks] = *(const s16x8*)(arow + ks * 32 + lk * 8);
  f32x4 C[9];
#pragma unroll
  for (int nf = 0; nf < 9; ++nf) C[nf] = (f32x4){0.f, 0.f, 0.f, 0.f};
#pragma unroll
  for (int ks = 0; ks < 4; ++ks)
#pragma unroll
    for (int nf = 0; nf < 9; ++nf) {
      const s16x8 b = *(const s16x8*)(PWo + (((ks * 4 + lk) * 144) + nf * 16 + n16) * 8);
      C[nf] = __builtin_amdgcn_mfma_f32_16x16x32_bf16(A[ks], b, C[nf], 0, 0, 0);
    }

#pragma unroll
  for (int nf = 0; nf < 8; ++nf) {
    const int col = nf * 16 + n16;
    const float bov = bo[col];
#pragma unroll
    for (int r = 0; r < 4; ++r) {
      const int row = lk * 4 + r;
      const long node = tile * 16 + row;
      const float res = resIn[node * DD + col] + bov + C[nf][r];
      if (NEXT) {
        resOut[node * DD + col] = res;
        tab[node * 160 + col] = f2bf(res);
      }
      st[row * 168 + col] = (short)f2bf(res);
    }
  }
  if (n16 == 0) {
#pragma unroll
    for (int r = 0; r < 4; ++r) {
      const int row = lk * 4 + r;
      const long node = tile * 16 + row;
      const float res = resIn[node * DD + 128] + bo[128] + C[8][r];
      if (NEXT) {
        resOut[node * DD + 128] = res;
        tab[node * 160 + 128] = f2bf(res);
      }
      st[row * 168 + 128] = (short)f2bf(res);
    }
  }

  s16x8 A5[5];
#pragma unroll
  for (int ks = 0; ks < 5; ++ks)
    A5[ks] = *(const s16x8*)(st + n16 * 168 + ks * 32 + lk * 8);

  if (NEXT) {
    f32x4 H[8];
#pragma unroll
    for (int nf = 0; nf < 8; ++nf) H[nf] = (f32x4){0.f, 0.f, 0.f, 0.f};
#pragma unroll
    for (int ks = 0; ks < 5; ++ks)
#pragma unroll
      for (int nf = 0; nf < 8; ++nf) {
        const s16x8 b = *(const s16x8*)(PW1mN + (((ks * 4 + lk) * 128) + nf * 16 + n16) * 8);
        H[nf] = __builtin_amdgcn_mfma_f32_16x16x32_bf16(A5[ks], b, H[nf], 0, 0, 0);
      }
#pragma unroll
    for (int nf = 0; nf < 8; ++nf) {
      const float bv = b1n[nf * 16 + n16];
#pragma unroll
      for (int r = 0; r < 4; ++r)
        HmOut[(long)(tile * 16 + lk * 4 + r) * HH + nf * 16 + n16] = H[nf][r] + bv;
    }
  } else {
    f32x4 Ch[4];
#pragma unroll
    for (int nf = 0; nf < 4; ++nf) Ch[nf] = (f32x4){0.f, 0.f, 0.f, 0.f};
#pragma unroll
    for (int ks = 0; ks < 5; ++ks)
#pragma unroll
      for (int nf = 0; nf < 4; ++nf) {
        const s16x8 b = *(const s16x8*)(PfW1 + (((ks * 4 + lk) * 64) + nf * 16 + n16) * 8);
        Ch[nf] = __builtin_amdgcn_mfma_f32_16x16x32_bf16(A5[ks], b, Ch[nf], 0, 0, 0);
      }
    float b1v[4], w2v[4];
#pragma unroll
    for (int nf = 0; nf < 4; ++nf) {
      b1v[nf] = fb1[nf * 16 + n16];
      w2v[nf] = fW2[nf * 16 + n16];
    }
#pragma unroll
    for (int r = 0; r < 4; ++r) {
      float s = 0.f;
#pragma unroll
      for (int nf = 0; nf < 4; ++nf)
        s += fmaxf(Ch[nf][r] + b1v[nf], 0.f) * w2v[nf];
      s += __shfl_xor(s, 1, 64);
      s += __shfl_xor(s, 2, 64);
      s += __shfl_xor(s, 4, 64);
      s += __shfl_xor(s, 8, 64);
      if (n16 == 0) outFinal[tile * 16 + lk * 4 + r] = s + fb2[0];
    }
  }
}

// ---------------------------------------------------------------------------
extern "C" void kernel_launch(void* const* d_in, const int* in_sizes, int n_in,
                              void* d_out, int out_size, void* d_ws, size_t ws_size,
                              hipStream_t stream) {
  const float* interp  = (const float*)d_in[0];
  const float* addInfo = (const float*)d_in[1];
  const int* sizes     = (const int*)d_in[2];
  const int* nbrIdx    = (const int*)d_in[3];
  const float* b0W1 = (const float*)d_in[5];
  const float* b0b1 = (const float*)d_in[6];
  const float* b0W2 = (const float*)d_in[7];
  const float* b0b2 = (const float*)d_in[8];
  const float* b0Wo = (const float*)d_in[9];
  const float* b0bo = (const float*)d_in[10];
  const float* b1W1 = (const float*)d_in[11];
  const float* b1b1 = (const float*)d_in[12];
  const float* b1W2 = (const float*)d_in[13];
  const float* b1b2 = (const float*)d_in[14];
  const float* b1Wo = (const float*)d_in[15];
  const float* b1bo = (const float*)d_in[16];
  const float* fW1  = (const float*)d_in[17];
  const float* fb1  = (const float*)d_in[18];
  const float* fW2  = (const float*)d_in[19];
  const float* fb2  = (const float*)d_in[20];

  char* ws = (char*)d_ws;
  int*            offs  = (int*)(ws + 0);                    // 65536
  short*          PA1   = (short*)(ws + 65536);              // 81920
  short*          PB2   = (short*)(ws + 147456);             // 65536
  short*          PWo   = (short*)(ws + 212992);             // 73728
  short*          PW1m  = (short*)(ws + 286720);             // 81920
  short*          PfW1  = (short*)(ws + 368640);             // 20480 -> pad
  unsigned short* TAB   = (unsigned short*)(ws + 393216);    // N*160*2
  float*          HM    = (float*)(ws + 5472256);            // N*128*4
  unsigned short* POOLED= (unsigned short*)(ws + 13598720);  // N*128*2
  float*          RES   = (float*)(ws + 17661952);           // N*129*4
  int*            SORTED= (int*)(ws + 25851904);             // N*4

  scan_sort_kernel<<<1, 256, 2 * NSEG * sizeof(int), stream>>>(sizes, offs,
                                                               SORTED);
  pack_tab_kernel<<<(PACKV + TABV) / 256, 256, 0, stream>>>(
      interp, TAB, b0W1, b1W1, b0W2, b1W2, b0Wo, b1Wo, fW1,
      PA1, PB2, PWo, PW1m, PfW1);

  const size_t e_lds = 40960 + 32768 + 8 * 32 * 136 * 2;  // 143360

  // ---- block 0 ----
  hmprep_kernel<<<NTILE / 4, 256, 0, stream>>>(TAB, PW1m, b0b1, HM);
  edge_kernel<<<256, 512, e_lds, stream>>>(TAB, PA1, PB2, b0W1, HM, addInfo,
                                           nbrIdx, offs, SORTED, b0b2, POOLED);
  resout_kernel<1><<<NTILE / 4, 256, 0, stream>>>(
      POOLED, PWo, b0bo, interp, RES, TAB, PW1m + 20480, b1b1, HM,
      nullptr, nullptr, nullptr, nullptr, nullptr);

  // ---- block 1 ----
  edge_kernel<<<256, 512, e_lds, stream>>>(TAB, PA1 + 20480, PB2 + 16384, b1W1,
                                           HM, addInfo, nbrIdx, offs, SORTED,
                                           b1b2, POOLED);
  resout_kernel<0><<<NTILE / 4, 256, 0, stream>>>(
      POOLED, PWo + 18432, b1bo, RES, nullptr, nullptr, nullptr, nullptr,
      nullptr, PfW1, fb1, fW2, fb2, (float*)d_out);
}